// Round 9
// baseline (1140.452 us; speedup 1.0000x reference)
//
#include <hip/hip_runtime.h>

#define BM 64
#define BN 64
#define BK 16
#define PAD 4

typedef double f64x4 __attribute__((ext_vector_type(4)));

// Dense fallback: C[m,h] = sum_d A[m,d] * W[h,d] + bias[h], fp64 accumulation.
template <typename PT>
__global__ __launch_bounds__(256) void gemm_nt(const float* __restrict__ A,
                                               const float* __restrict__ W,
                                               const float* __restrict__ bias,
                                               PT* __restrict__ C,
                                               int M, int D, int H) {
    __shared__ float As[BK][BM + PAD];
    __shared__ float Ws[BK][BN + PAD];
    const int tid = threadIdx.x;
    const int tx = tid & 15;
    const int ty = tid >> 4;
    const int row0 = blockIdx.x * BM;
    const int col0 = blockIdx.y * BN;
    const int lr = tid >> 2;
    const int lk = (tid & 3) << 2;

    double acc[4][4];
#pragma unroll
    for (int i = 0; i < 4; ++i)
#pragma unroll
        for (int j = 0; j < 4; ++j)
            acc[i][j] = (double)bias[col0 + tx * 4 + j];

    const float* Aptr = A + (size_t)(row0 + lr) * D + lk;
    const float* Wptr = W + (size_t)(col0 + lr) * D + lk;

    for (int kk = 0; kk < D; kk += BK) {
        float4 av = *reinterpret_cast<const float4*>(Aptr + kk);
        float4 wv = *reinterpret_cast<const float4*>(Wptr + kk);
        __syncthreads();
        As[lk + 0][lr] = av.x; As[lk + 1][lr] = av.y;
        As[lk + 2][lr] = av.z; As[lk + 3][lr] = av.w;
        Ws[lk + 0][lr] = wv.x; Ws[lk + 1][lr] = wv.y;
        Ws[lk + 2][lr] = wv.z; Ws[lk + 3][lr] = wv.w;
        __syncthreads();
#pragma unroll
        for (int k = 0; k < BK; ++k) {
            float a[4], w[4];
#pragma unroll
            for (int i = 0; i < 4; ++i) a[i] = As[k][ty * 4 + i];
#pragma unroll
            for (int j = 0; j < 4; ++j) w[j] = Ws[k][tx * 4 + j];
#pragma unroll
            for (int i = 0; i < 4; ++i)
#pragma unroll
                for (int j = 0; j < 4; ++j)
                    acc[i][j] += (double)a[i] * (double)w[j];
        }
    }
#pragma unroll
    for (int i = 0; i < 4; ++i) {
        size_t r = (size_t)(row0 + ty * 4 + i) * H + col0 + tx * 4;
#pragma unroll
        for (int j = 0; j < 4; ++j)
            C[r + j] = (PT)acc[i][j];
    }
}

// fp64-MFMA dense GEMM: P[m,h] = sum_d A[m,d]*W[h,d] + bias[h].
// 64x64 tile, 4 waves x (16 rows x 64 cols), K-step 16, 2-stage reg prefetch.
// C/D row mapping self-discovered via probe MFMA (proven R8).
__global__ __launch_bounds__(256) void gemm_f64mfma(const float* __restrict__ A,
                                                    const float* __restrict__ W,
                                                    const float* __restrict__ bias,
                                                    double* __restrict__ P,
                                                    int M, int D, int H) {
    __shared__ float As[64][20];
    __shared__ float Bs[64][20];
    const int tid = threadIdx.x;
    const int wave = tid >> 6, lane = tid & 63;
    const int l15 = lane & 15, l4 = lane >> 4;
    const int row0 = blockIdx.x * 64, col0 = blockIdx.y * 64;
    const int lrow = tid >> 2;
    const int lk4 = (tid & 3) << 2;

    // Layout probe: D[i][j] = i; reg r then holds its own row index.
    int rowidx[4];
    {
        double pa = (l4 == 0) ? (double)l15 : 0.0;  // A[r][0] = r
        double pb = (l4 == 0) ? 1.0 : 0.0;          // B[0][c] = 1
        f64x4 pd = {0.0, 0.0, 0.0, 0.0};
        pd = __builtin_amdgcn_mfma_f64_16x16x4f64(pa, pb, pd, 0, 0, 0);
#pragma unroll
        for (int i = 0; i < 4; ++i) rowidx[i] = (int)pd[i];
    }

    f64x4 acc[4];
#pragma unroll
    for (int ct = 0; ct < 4; ++ct) {
        double bv = (double)bias[col0 + ct * 16 + l15];
        acc[ct][0] = bv; acc[ct][1] = bv; acc[ct][2] = bv; acc[ct][3] = bv;
    }

    const float* Aptr = A + (size_t)(row0 + lrow) * D + lk4;
    const float* Wptr = W + (size_t)(col0 + lrow) * D + lk4;

    // 2-stage register prefetch: next tile's global loads issue before MFMAs.
    float4 av = *reinterpret_cast<const float4*>(Aptr);
    float4 wv = *reinterpret_cast<const float4*>(Wptr);

    for (int k0 = 0; k0 < D; k0 += 16) {
        __syncthreads();
        *reinterpret_cast<float4*>(&As[lrow][lk4]) = av;
        *reinterpret_cast<float4*>(&Bs[lrow][lk4]) = wv;
        __syncthreads();
        if (k0 + 16 < D) {
            av = *reinterpret_cast<const float4*>(Aptr + k0 + 16);
            wv = *reinterpret_cast<const float4*>(Wptr + k0 + 16);
        }
#pragma unroll
        for (int ks = 0; ks < 4; ++ks) {
            double a = (double)As[wave * 16 + l15][ks * 4 + l4];
#pragma unroll
            for (int ct = 0; ct < 4; ++ct) {
                double b = (double)Bs[ct * 16 + l15][ks * 4 + l4];
                acc[ct] = __builtin_amdgcn_mfma_f64_16x16x4f64(a, b, acc[ct], 0, 0, 0);
            }
        }
    }
#pragma unroll
    for (int ct = 0; ct < 4; ++ct) {
#pragma unroll
        for (int i = 0; i < 4; ++i) {
            size_t row = (size_t)(row0 + wave * 16 + rowidx[i]);
            P[row * H + col0 + ct * 16 + l15] = acc[ct][i];
        }
    }
}

// 1024x1024 transpose: Wt[d][h] = W[h][d]
__global__ __launch_bounds__(256) void transpose_w(const float* __restrict__ W,
                                                   float* __restrict__ Wt) {
    __shared__ float t[32][33];
    const int N = 1024;
    const int bx = blockIdx.x * 32, by = blockIdx.y * 32;
    int x = bx + threadIdx.x;
    int y = by + threadIdx.y;
#pragma unroll
    for (int j = 0; j < 32; j += 8)
        t[threadIdx.y + j][threadIdx.x] = W[(size_t)(y + j) * N + x];
    __syncthreads();
    x = by + threadIdx.x;
    y = bx + threadIdx.y;
#pragma unroll
    for (int j = 0; j < 32; j += 8)
        Wt[(size_t)(y + j) * N + x] = t[threadIdx.x][threadIdx.y + j];
}

// Sparse spike layer: P[m,h] = bias[h] + sum_{d: S[m,d]!=0} Wt[d][h]
// 16 rows/block; union active-list with 16-bit row masks; branchy masked adds
// + 4-deep prefetch. __launch_bounds__(256,2): VGPR cap 256 >= ~190 demand
// (acc[16][4]=128 + pipeline 32 + misc) -> no spill (R6-proven config).
__global__ __launch_bounds__(256, 2) void spike_gemm16b(const float* __restrict__ S,
                                                        const float* __restrict__ Wt,
                                                        const float* __restrict__ bias,
                                                        double* __restrict__ P) {
    __shared__ int idx[1024];
    __shared__ int cnts[4];
    const int tid = threadIdx.x;
    const int wave = tid >> 6;
    const int lane = tid & 63;
    const int m0 = blockIdx.x * 16;

    // Phase 1: per-wave ballot compaction; pad to multiple of 4 with (d=0,mask=0).
    int base = 0;
#pragma unroll
    for (int jj = 0; jj < 4; ++jj) {
        const int d = wave * 256 + jj * 64 + lane;
        unsigned mask = 0;
#pragma unroll
        for (int r = 0; r < 16; ++r) {
            float s = S[(((size_t)(m0 + r)) << 10) + d];
            mask |= (s != 0.0f) ? (1u << r) : 0u;
        }
        unsigned long long b = __ballot(mask != 0);
        int pos = __popcll(b & ((1ull << lane) - 1ull));
        if (mask) idx[wave * 256 + base + pos] = d | (int)(mask << 16);
        base += __popcll(b);
    }
    if (lane == 0) {
        int padded = (base + 3) & ~3;
        for (int j = base; j < padded; ++j) idx[wave * 256 + j] = 0;  // d=0, mask=0
        cnts[wave] = padded;
    }
    __syncthreads();

    // Phase 2: branchy masked fp64 accumulation, 4-deep prefetch.
    const int h0 = tid * 4;
    double acc[16][4];
    {
        double bv[4];
#pragma unroll
        for (int j = 0; j < 4; ++j) bv[j] = (double)bias[h0 + j];
#pragma unroll
        for (int r = 0; r < 16; ++r)
#pragma unroll
            for (int j = 0; j < 4; ++j) acc[r][j] = bv[j];
    }

#define PROCB(WV, CM)                                                   \
    {                                                                   \
        const unsigned cm_ = (CM);                                      \
        if (cm_) {                                                      \
            const double d0 = (double)(WV).x, d1 = (double)(WV).y,      \
                         d2 = (double)(WV).z, d3 = (double)(WV).w;      \
            _Pragma("unroll")                                           \
            for (int r = 0; r < 16; ++r) {                              \
                if (cm_ & (1u << r)) {                                  \
                    acc[r][0] += d0; acc[r][1] += d1;                   \
                    acc[r][2] += d2; acc[r][3] += d3;                   \
                }                                                       \
            }                                                           \
        }                                                               \
    }

    for (int s = 0; s < 4; ++s) {
        const int cnt = cnts[s];  // multiple of 4
        if (cnt == 0) continue;
        const int* seg = idx + s * 256;
        unsigned e0 = (unsigned)__builtin_amdgcn_readfirstlane(seg[0]);
        unsigned e1 = (unsigned)__builtin_amdgcn_readfirstlane(seg[1]);
        unsigned e2 = (unsigned)__builtin_amdgcn_readfirstlane(seg[2]);
        unsigned e3 = (unsigned)__builtin_amdgcn_readfirstlane(seg[3]);
        float4 w0 = *reinterpret_cast<const float4*>(Wt + (((size_t)(e0 & 0x3FFu)) << 10) + h0);
        float4 w1 = *reinterpret_cast<const float4*>(Wt + (((size_t)(e1 & 0x3FFu)) << 10) + h0);
        float4 w2 = *reinterpret_cast<const float4*>(Wt + (((size_t)(e2 & 0x3FFu)) << 10) + h0);
        float4 w3 = *reinterpret_cast<const float4*>(Wt + (((size_t)(e3 & 0x3FFu)) << 10) + h0);
        for (int i = 0; i < cnt; i += 4) {
            unsigned n0 = 0, n1 = 0, n2 = 0, n3 = 0;
            float4 x0 = {0, 0, 0, 0}, x1 = {0, 0, 0, 0}, x2 = {0, 0, 0, 0}, x3 = {0, 0, 0, 0};
            if (i + 4 < cnt) {
                n0 = (unsigned)__builtin_amdgcn_readfirstlane(seg[i + 4]);
                n1 = (unsigned)__builtin_amdgcn_readfirstlane(seg[i + 5]);
                n2 = (unsigned)__builtin_amdgcn_readfirstlane(seg[i + 6]);
                n3 = (unsigned)__builtin_amdgcn_readfirstlane(seg[i + 7]);
                x0 = *reinterpret_cast<const float4*>(Wt + (((size_t)(n0 & 0x3FFu)) << 10) + h0);
                x1 = *reinterpret_cast<const float4*>(Wt + (((size_t)(n1 & 0x3FFu)) << 10) + h0);
                x2 = *reinterpret_cast<const float4*>(Wt + (((size_t)(n2 & 0x3FFu)) << 10) + h0);
                x3 = *reinterpret_cast<const float4*>(Wt + (((size_t)(n3 & 0x3FFu)) << 10) + h0);
            }
            PROCB(w0, e0 >> 16);
            PROCB(w1, e1 >> 16);
            PROCB(w2, e2 >> 16);
            PROCB(w3, e3 >> 16);
            e0 = n0; e1 = n1; e2 = n2; e3 = n3;
            w0 = x0; w1 = x1; w2 = x2; w3 = x3;
        }
    }
#undef PROCB

    // Phase 3: write P
#pragma unroll
    for (int r = 0; r < 16; ++r) {
        double* p = P + (((size_t)(m0 + r)) << 10) + h0;
        p[0] = acc[r][0]; p[1] = acc[r][1]; p[2] = acc[r][2]; p[3] = acc[r][3];
    }
}

// Serial LIF over t for each (b,h) chain.
template <typename PT>
__global__ __launch_bounds__(256) void lif_scan(const PT* __restrict__ P,
                                                float* __restrict__ S,
                                                int B, int T, int H) {
    const int g = blockIdx.x * blockDim.x + threadIdx.x;
    if (g >= B * H) return;
    const int h = g & (H - 1);
    const int b = g / H;
    const size_t base = (size_t)b * T * H + h;
    double u = 0.0;
    for (int t0 = 0; t0 < T; t0 += 8) {
        double I[8];
#pragma unroll
        for (int j = 0; j < 8; ++j)
            I[j] = (double)P[base + (size_t)(t0 + j) * H];
#pragma unroll
        for (int j = 0; j < 8; ++j) {
            u = 0.5 * u + I[j];
            float s;
            if (u >= 0.5) { s = 1.0f; u = 0.0; } else { s = 0.0f; }
            S[base + (size_t)(t0 + j) * H] = s;
        }
    }
}

extern "C" void kernel_launch(void* const* d_in, const int* in_sizes, int n_in,
                              void* d_out, int out_size, void* d_ws, size_t ws_size,
                              hipStream_t stream) {
    const float* x  = (const float*)d_in[0];
    const float* W0 = (const float*)d_in[1];
    const float* b0 = (const float*)d_in[2];
    const float* W1 = (const float*)d_in[3];
    const float* b1 = (const float*)d_in[4];
    const float* W2 = (const float*)d_in[5];
    const float* b2 = (const float*)d_in[6];

    const int B = 32, T = 512, D0 = 512, H = 1024;
    const int M = B * T;  // 16384

    float* S = (float*)d_out;

    dim3 gemm_grid(M / BM, H / BN);
    const int scan_blocks = (B * H) / 256;

    const size_t P_bytes = (size_t)M * H * sizeof(double);   // 128 MB
    const size_t need_sparse = P_bytes + (size_t)H * H * 4;  // + 4 MB Wt

    if (ws_size >= need_sparse) {
        double* P = (double*)d_ws;
        float* Wt = (float*)((char*)d_ws + P_bytes);
        dim3 tgrid(H / 32, H / 32);
        dim3 tblk(32, 8);

        // Layer 0: dense fp64 MFMA GEMM (probe layout + 2-stage prefetch).
        gemm_f64mfma<<<dim3(M / 64, H / 64), 256, 0, stream>>>(x, W0, b0, P, M, D0, H);
        lif_scan<double><<<scan_blocks, 256, 0, stream>>>(P, S, B, T, H);

        // Layer 1: sparse (binary spikes), 16 rows/block
        transpose_w<<<tgrid, tblk, 0, stream>>>(W1, Wt);
        spike_gemm16b<<<M / 16, 256, 0, stream>>>(S, Wt, b1, P);
        lif_scan<double><<<scan_blocks, 256, 0, stream>>>(P, S, B, T, H);

        // Layer 2: sparse
        transpose_w<<<tgrid, tblk, 0, stream>>>(W2, Wt);
        spike_gemm16b<<<M / 16, 256, 0, stream>>>(S, Wt, b2, P);
        lif_scan<double><<<scan_blocks, 256, 0, stream>>>(P, S, B, T, H);
    } else if (ws_size >= P_bytes) {
        double* P = (double*)d_ws;
        gemm_nt<double><<<gemm_grid, 256, 0, stream>>>(x, W0, b0, P, M, D0, H);
        lif_scan<double><<<scan_blocks, 256, 0, stream>>>(P, S, B, T, H);
        gemm_nt<double><<<gemm_grid, 256, 0, stream>>>(S, W1, b1, P, M, H, H);
        lif_scan<double><<<scan_blocks, 256, 0, stream>>>(P, S, B, T, H);
        gemm_nt<double><<<gemm_grid, 256, 0, stream>>>(S, W2, b2, P, M, H, H);
        lif_scan<double><<<scan_blocks, 256, 0, stream>>>(P, S, B, T, H);
    } else {
        float* P = (float*)d_ws;
        gemm_nt<float><<<gemm_grid, 256, 0, stream>>>(x, W0, b0, P, M, D0, H);
        lif_scan<float><<<scan_blocks, 256, 0, stream>>>(P, S, B, T, H);
        gemm_nt<float><<<gemm_grid, 256, 0, stream>>>(S, W1, b1, P, M, H, H);
        lif_scan<float><<<scan_blocks, 256, 0, stream>>>(P, S, B, T, H);
        gemm_nt<float><<<gemm_grid, 256, 0, stream>>>(S, W2, b2, P, M, H, H);
        lif_scan<float><<<scan_blocks, 256, 0, stream>>>(P, S, B, T, H);
    }
}

// Round 10
// 845.824 us; speedup vs baseline: 1.3483x; 1.3483x over previous
//
#include <hip/hip_runtime.h>

#define BM 64
#define BN 64
#define BK 16
#define PAD 4

typedef double f64x4 __attribute__((ext_vector_type(4)));

// Dense fallback: C[m,h] = sum_d A[m,d] * W[h,d] + bias[h], fp64 accumulation.
template <typename PT>
__global__ __launch_bounds__(256) void gemm_nt(const float* __restrict__ A,
                                               const float* __restrict__ W,
                                               const float* __restrict__ bias,
                                               PT* __restrict__ C,
                                               int M, int D, int H) {
    __shared__ float As[BK][BM + PAD];
    __shared__ float Ws[BK][BN + PAD];
    const int tid = threadIdx.x;
    const int tx = tid & 15;
    const int ty = tid >> 4;
    const int row0 = blockIdx.x * BM;
    const int col0 = blockIdx.y * BN;
    const int lr = tid >> 2;
    const int lk = (tid & 3) << 2;

    double acc[4][4];
#pragma unroll
    for (int i = 0; i < 4; ++i)
#pragma unroll
        for (int j = 0; j < 4; ++j)
            acc[i][j] = (double)bias[col0 + tx * 4 + j];

    const float* Aptr = A + (size_t)(row0 + lr) * D + lk;
    const float* Wptr = W + (size_t)(col0 + lr) * D + lk;

    for (int kk = 0; kk < D; kk += BK) {
        float4 av = *reinterpret_cast<const float4*>(Aptr + kk);
        float4 wv = *reinterpret_cast<const float4*>(Wptr + kk);
        __syncthreads();
        As[lk + 0][lr] = av.x; As[lk + 1][lr] = av.y;
        As[lk + 2][lr] = av.z; As[lk + 3][lr] = av.w;
        Ws[lk + 0][lr] = wv.x; Ws[lk + 1][lr] = wv.y;
        Ws[lk + 2][lr] = wv.z; Ws[lk + 3][lr] = wv.w;
        __syncthreads();
#pragma unroll
        for (int k = 0; k < BK; ++k) {
            float a[4], w[4];
#pragma unroll
            for (int i = 0; i < 4; ++i) a[i] = As[k][ty * 4 + i];
#pragma unroll
            for (int j = 0; j < 4; ++j) w[j] = Ws[k][tx * 4 + j];
#pragma unroll
            for (int i = 0; i < 4; ++i)
#pragma unroll
                for (int j = 0; j < 4; ++j)
                    acc[i][j] += (double)a[i] * (double)w[j];
        }
    }
#pragma unroll
    for (int i = 0; i < 4; ++i) {
        size_t r = (size_t)(row0 + ty * 4 + i) * H + col0 + tx * 4;
#pragma unroll
        for (int j = 0; j < 4; ++j)
            C[r + j] = (PT)acc[i][j];
    }
}

// fp64-MFMA dense GEMM: P[m,h] = sum_d A[m,d]*W[h,d] + bias[h].
// 64x64 tile, 4 waves x (16 rows x 64 cols), K-step 32 (halved barrier count
// vs R8's 16). C/D row mapping self-discovered via probe MFMA (proven R8).
__global__ __launch_bounds__(256) void gemm_f64mfma(const float* __restrict__ A,
                                                    const float* __restrict__ W,
                                                    const float* __restrict__ bias,
                                                    double* __restrict__ P,
                                                    int M, int D, int H) {
    __shared__ float As[64][36];  // [row][k], 32 k + pad 4
    __shared__ float Bs[64][36];
    const int tid = threadIdx.x;
    const int wave = tid >> 6, lane = tid & 63;
    const int l15 = lane & 15, l4 = lane >> 4;
    const int row0 = blockIdx.x * 64, col0 = blockIdx.y * 64;
    const int lrow = tid >> 2;        // 0..63 staging row
    const int lk8 = (tid & 3) << 3;   // 0,8,16,24: 8-float slice per thread

    // Layout probe: D[i][j] = i; reg r then holds its own row index.
    int rowidx[4];
    {
        double pa = (l4 == 0) ? (double)l15 : 0.0;  // A[r][0] = r
        double pb = (l4 == 0) ? 1.0 : 0.0;          // B[0][c] = 1
        f64x4 pd = {0.0, 0.0, 0.0, 0.0};
        pd = __builtin_amdgcn_mfma_f64_16x16x4f64(pa, pb, pd, 0, 0, 0);
#pragma unroll
        for (int i = 0; i < 4; ++i) rowidx[i] = (int)pd[i];
    }

    f64x4 acc[4];
#pragma unroll
    for (int ct = 0; ct < 4; ++ct) {
        double bv = (double)bias[col0 + ct * 16 + l15];
        acc[ct][0] = bv; acc[ct][1] = bv; acc[ct][2] = bv; acc[ct][3] = bv;
    }

    const float* Aptr = A + (size_t)(row0 + lrow) * D + lk8;
    const float* Wptr = W + (size_t)(col0 + lrow) * D + lk8;

    for (int k0 = 0; k0 < D; k0 += 32) {
        float4 av0 = *reinterpret_cast<const float4*>(Aptr + k0);
        float4 av1 = *reinterpret_cast<const float4*>(Aptr + k0 + 4);
        float4 wv0 = *reinterpret_cast<const float4*>(Wptr + k0);
        float4 wv1 = *reinterpret_cast<const float4*>(Wptr + k0 + 4);
        __syncthreads();
        *reinterpret_cast<float4*>(&As[lrow][lk8]) = av0;
        *reinterpret_cast<float4*>(&As[lrow][lk8 + 4]) = av1;
        *reinterpret_cast<float4*>(&Bs[lrow][lk8]) = wv0;
        *reinterpret_cast<float4*>(&Bs[lrow][lk8 + 4]) = wv1;
        __syncthreads();
#pragma unroll
        for (int ks = 0; ks < 8; ++ks) {
            double a = (double)As[wave * 16 + l15][ks * 4 + l4];
#pragma unroll
            for (int ct = 0; ct < 4; ++ct) {
                double b = (double)Bs[ct * 16 + l15][ks * 4 + l4];
                acc[ct] = __builtin_amdgcn_mfma_f64_16x16x4f64(a, b, acc[ct], 0, 0, 0);
            }
        }
    }
#pragma unroll
    for (int ct = 0; ct < 4; ++ct) {
#pragma unroll
        for (int i = 0; i < 4; ++i) {
            size_t row = (size_t)(row0 + wave * 16 + rowidx[i]);
            P[row * H + col0 + ct * 16 + l15] = acc[ct][i];
        }
    }
}

// 1024x1024 transpose: Wt[d][h] = W[h][d]
__global__ __launch_bounds__(256) void transpose_w(const float* __restrict__ W,
                                                   float* __restrict__ Wt) {
    __shared__ float t[32][33];
    const int N = 1024;
    const int bx = blockIdx.x * 32, by = blockIdx.y * 32;
    int x = bx + threadIdx.x;
    int y = by + threadIdx.y;
#pragma unroll
    for (int j = 0; j < 32; j += 8)
        t[threadIdx.y + j][threadIdx.x] = W[(size_t)(y + j) * N + x];
    __syncthreads();
    x = by + threadIdx.x;
    y = bx + threadIdx.y;
#pragma unroll
    for (int j = 0; j < 32; j += 8)
        Wt[(size_t)(y + j) * N + x] = t[threadIdx.x][threadIdx.y + j];
}

// Sparse spike layer: P[m,h] = bias[h] + sum_{d: S[m,d]!=0} Wt[d][h]
// 8 rows/block; union active-list with 8-bit row masks; branchy masked adds
// (wave-uniform scalar mask -> cheap SALU skips) + 4-deep prefetch.
// FROZEN R8 config: 16-row variants spill (R3, R9) -- do not revisit.
__global__ __launch_bounds__(256, 2) void spike_gemm8p4(const float* __restrict__ S,
                                                        const float* __restrict__ Wt,
                                                        const float* __restrict__ bias,
                                                        double* __restrict__ P) {
    __shared__ int idx[1024];
    __shared__ int cnts[4];
    const int tid = threadIdx.x;
    const int wave = tid >> 6;
    const int lane = tid & 63;
    const int m0 = blockIdx.x * 8;

    // Phase 1: per-wave ballot compaction; pad to multiple of 4 with (d=0,mask=0).
    int base = 0;
#pragma unroll
    for (int jj = 0; jj < 4; ++jj) {
        const int d = wave * 256 + jj * 64 + lane;
        unsigned mask8 = 0;
#pragma unroll
        for (int r = 0; r < 8; ++r) {
            float s = S[(((size_t)(m0 + r)) << 10) + d];
            mask8 |= (s != 0.0f) ? (1u << r) : 0u;
        }
        unsigned long long b = __ballot(mask8 != 0);
        int pos = __popcll(b & ((1ull << lane) - 1ull));
        if (mask8) idx[wave * 256 + base + pos] = d | (int)(mask8 << 16);
        base += __popcll(b);
    }
    if (lane == 0) {
        int padded = (base + 3) & ~3;
        for (int j = base; j < padded; ++j) idx[wave * 256 + j] = 0;  // d=0, mask=0
        cnts[wave] = padded;
    }
    __syncthreads();

    // Phase 2: branchy masked fp64 accumulation, 4-deep prefetch.
    const int h0 = tid * 4;
    double acc[8][4];
    {
        double bv[4];
#pragma unroll
        for (int j = 0; j < 4; ++j) bv[j] = (double)bias[h0 + j];
#pragma unroll
        for (int r = 0; r < 8; ++r)
#pragma unroll
            for (int j = 0; j < 4; ++j) acc[r][j] = bv[j];
    }

#define PROCB(WV, CM)                                                   \
    {                                                                   \
        const unsigned cm_ = (CM);                                      \
        if (cm_) {                                                      \
            const double d0 = (double)(WV).x, d1 = (double)(WV).y,      \
                         d2 = (double)(WV).z, d3 = (double)(WV).w;      \
            _Pragma("unroll")                                           \
            for (int r = 0; r < 8; ++r) {                               \
                if (cm_ & (1u << r)) {                                  \
                    acc[r][0] += d0; acc[r][1] += d1;                   \
                    acc[r][2] += d2; acc[r][3] += d3;                   \
                }                                                       \
            }                                                           \
        }                                                               \
    }

    for (int s = 0; s < 4; ++s) {
        const int cnt = cnts[s];  // multiple of 4
        if (cnt == 0) continue;
        const int* seg = idx + s * 256;
        unsigned e0 = (unsigned)__builtin_amdgcn_readfirstlane(seg[0]);
        unsigned e1 = (unsigned)__builtin_amdgcn_readfirstlane(seg[1]);
        unsigned e2 = (unsigned)__builtin_amdgcn_readfirstlane(seg[2]);
        unsigned e3 = (unsigned)__builtin_amdgcn_readfirstlane(seg[3]);
        float4 w0 = *reinterpret_cast<const float4*>(Wt + (((size_t)(e0 & 0x3FFu)) << 10) + h0);
        float4 w1 = *reinterpret_cast<const float4*>(Wt + (((size_t)(e1 & 0x3FFu)) << 10) + h0);
        float4 w2 = *reinterpret_cast<const float4*>(Wt + (((size_t)(e2 & 0x3FFu)) << 10) + h0);
        float4 w3 = *reinterpret_cast<const float4*>(Wt + (((size_t)(e3 & 0x3FFu)) << 10) + h0);
        for (int i = 0; i < cnt; i += 4) {
            unsigned n0 = 0, n1 = 0, n2 = 0, n3 = 0;
            float4 x0 = {0, 0, 0, 0}, x1 = {0, 0, 0, 0}, x2 = {0, 0, 0, 0}, x3 = {0, 0, 0, 0};
            if (i + 4 < cnt) {
                n0 = (unsigned)__builtin_amdgcn_readfirstlane(seg[i + 4]);
                n1 = (unsigned)__builtin_amdgcn_readfirstlane(seg[i + 5]);
                n2 = (unsigned)__builtin_amdgcn_readfirstlane(seg[i + 6]);
                n3 = (unsigned)__builtin_amdgcn_readfirstlane(seg[i + 7]);
                x0 = *reinterpret_cast<const float4*>(Wt + (((size_t)(n0 & 0x3FFu)) << 10) + h0);
                x1 = *reinterpret_cast<const float4*>(Wt + (((size_t)(n1 & 0x3FFu)) << 10) + h0);
                x2 = *reinterpret_cast<const float4*>(Wt + (((size_t)(n2 & 0x3FFu)) << 10) + h0);
                x3 = *reinterpret_cast<const float4*>(Wt + (((size_t)(n3 & 0x3FFu)) << 10) + h0);
            }
            PROCB(w0, e0 >> 16);
            PROCB(w1, e1 >> 16);
            PROCB(w2, e2 >> 16);
            PROCB(w3, e3 >> 16);
            e0 = n0; e1 = n1; e2 = n2; e3 = n3;
            w0 = x0; w1 = x1; w2 = x2; w3 = x3;
        }
    }
#undef PROCB

    // Phase 3: write P
#pragma unroll
    for (int r = 0; r < 8; ++r) {
        double* p = P + (((size_t)(m0 + r)) << 10) + h0;
        p[0] = acc[r][0]; p[1] = acc[r][1]; p[2] = acc[r][2]; p[3] = acc[r][3];
    }
}

// Serial LIF over t for each (b,h) chain.
template <typename PT>
__global__ __launch_bounds__(256) void lif_scan(const PT* __restrict__ P,
                                                float* __restrict__ S,
                                                int B, int T, int H) {
    const int g = blockIdx.x * blockDim.x + threadIdx.x;
    if (g >= B * H) return;
    const int h = g & (H - 1);
    const int b = g / H;
    const size_t base = (size_t)b * T * H + h;
    double u = 0.0;
    for (int t0 = 0; t0 < T; t0 += 8) {
        double I[8];
#pragma unroll
        for (int j = 0; j < 8; ++j)
            I[j] = (double)P[base + (size_t)(t0 + j) * H];
#pragma unroll
        for (int j = 0; j < 8; ++j) {
            u = 0.5 * u + I[j];
            float s;
            if (u >= 0.5) { s = 1.0f; u = 0.0; } else { s = 0.0f; }
            S[base + (size_t)(t0 + j) * H] = s;
        }
    }
}

extern "C" void kernel_launch(void* const* d_in, const int* in_sizes, int n_in,
                              void* d_out, int out_size, void* d_ws, size_t ws_size,
                              hipStream_t stream) {
    const float* x  = (const float*)d_in[0];
    const float* W0 = (const float*)d_in[1];
    const float* b0 = (const float*)d_in[2];
    const float* W1 = (const float*)d_in[3];
    const float* b1 = (const float*)d_in[4];
    const float* W2 = (const float*)d_in[5];
    const float* b2 = (const float*)d_in[6];

    const int B = 32, T = 512, D0 = 512, H = 1024;
    const int M = B * T;  // 16384

    float* S = (float*)d_out;

    dim3 gemm_grid(M / BM, H / BN);
    const int scan_blocks = (B * H) / 256;

    const size_t P_bytes = (size_t)M * H * sizeof(double);   // 128 MB
    const size_t need_sparse = P_bytes + (size_t)H * H * 4;  // + 4 MB Wt

    if (ws_size >= need_sparse) {
        double* P = (double*)d_ws;
        float* Wt = (float*)((char*)d_ws + P_bytes);
        dim3 tgrid(H / 32, H / 32);
        dim3 tblk(32, 8);

        // Layer 0: dense fp64 MFMA GEMM (probe layout, BK=32).
        gemm_f64mfma<<<dim3(M / 64, H / 64), 256, 0, stream>>>(x, W0, b0, P, M, D0, H);
        lif_scan<double><<<scan_blocks, 256, 0, stream>>>(P, S, B, T, H);

        // Layer 1: sparse (binary spikes), frozen 8-row config
        transpose_w<<<tgrid, tblk, 0, stream>>>(W1, Wt);
        spike_gemm8p4<<<M / 8, 256, 0, stream>>>(S, Wt, b1, P);
        lif_scan<double><<<scan_blocks, 256, 0, stream>>>(P, S, B, T, H);

        // Layer 2: sparse
        transpose_w<<<tgrid, tblk, 0, stream>>>(W2, Wt);
        spike_gemm8p4<<<M / 8, 256, 0, stream>>>(S, Wt, b2, P);
        lif_scan<double><<<scan_blocks, 256, 0, stream>>>(P, S, B, T, H);
    } else if (ws_size >= P_bytes) {
        double* P = (double*)d_ws;
        gemm_nt<double><<<gemm_grid, 256, 0, stream>>>(x, W0, b0, P, M, D0, H);
        lif_scan<double><<<scan_blocks, 256, 0, stream>>>(P, S, B, T, H);
        gemm_nt<double><<<gemm_grid, 256, 0, stream>>>(S, W1, b1, P, M, H, H);
        lif_scan<double><<<scan_blocks, 256, 0, stream>>>(P, S, B, T, H);
        gemm_nt<double><<<gemm_grid, 256, 0, stream>>>(S, W2, b2, P, M, H, H);
        lif_scan<double><<<scan_blocks, 256, 0, stream>>>(P, S, B, T, H);
    } else {
        float* P = (float*)d_ws;
        gemm_nt<float><<<gemm_grid, 256, 0, stream>>>(x, W0, b0, P, M, D0, H);
        lif_scan<float><<<scan_blocks, 256, 0, stream>>>(P, S, B, T, H);
        gemm_nt<float><<<gemm_grid, 256, 0, stream>>>(S, W1, b1, P, M, H, H);
        lif_scan<float><<<scan_blocks, 256, 0, stream>>>(P, S, B, T, H);
        gemm_nt<float><<<gemm_grid, 256, 0, stream>>>(S, W2, b2, P, M, H, H);
        lif_scan<float><<<scan_blocks, 256, 0, stream>>>(P, S, B, T, H);
    }
}